// Round 8
// baseline (102.688 us; speedup 1.0000x reference)
//
#include <hip/hip_runtime.h>
#include <hip/hip_fp16.h>
#include <math.h>

#define FIN_ 128

typedef _Float16 half2v __attribute__((ext_vector_type(2)));
typedef _Float16 half8v __attribute__((ext_vector_type(8)));
typedef __attribute__((ext_vector_type(4))) float float4v;

__device__ __forceinline__ half2v u2h(unsigned u) {
    union { unsigned u; half2v h; } c; c.u = u; return c.h;
}

// ---------------- fused fp32->f16 convert (x, W) + rowptr build ----------------
__global__ __launch_bounds__(256) void cvt_and_rowptr(const float* __restrict__ x,
                                                      const float* __restrict__ W,
                                                      _Float16* __restrict__ xh,
                                                      _Float16* __restrict__ wh,
                                                      const int* __restrict__ src,
                                                      int* __restrict__ rowptr,
                                                      int nx8, int nw8, int nE, int n) {
    int i = blockIdx.x * blockDim.x + threadIdx.x;
    if (i < nx8 + nw8) {
        const float* s;
        _Float16* d;
        if (i < nx8) { s = x + (size_t)i * 8; d = xh + (size_t)i * 8; }
        else { s = W + (size_t)(i - nx8) * 8; d = wh + (size_t)(i - nx8) * 8; }
        const float4 a = *(const float4*)s;
        const float4 b = *(const float4*)(s + 4);
        half8v r;
        r[0] = (_Float16)a.x; r[1] = (_Float16)a.y;
        r[2] = (_Float16)a.z; r[3] = (_Float16)a.w;
        r[4] = (_Float16)b.x; r[5] = (_Float16)b.y;
        r[6] = (_Float16)b.z; r[7] = (_Float16)b.w;
        *(half8v*)d = r;
    } else {
        const int j = i - (nx8 + nw8);
        if (j > n) return;
        int lo = 0, hi = nE;
        while (lo < hi) {
            int mid = (lo + hi) >> 1;
            if (src[mid] < j) lo = mid + 1; else hi = mid;
        }
        rowptr[j] = lo;
    }
}

// ---------------- f16 MFMA GEMM from pre-converted inputs, swapped operands ----------
// A = W rows (features), B = x rows (nodes); C[feat][node]. Staging = pure 16B
// copies (no convert VALU). Epilogue via LDS transpose tile -> 8 coalesced 16B
// stores/thread.
//   fblk 0 -> q*0.25 into qb[node][128]; fblk 1 -> k into kv[node][0..127];
//   fblk 2 -> v into kv[node][128..255]
__global__ __launch_bounds__(256) void gemm_qkv_mfma(const _Float16* __restrict__ xh,
                                                     const _Float16* __restrict__ wh,
                                                     _Float16* __restrict__ qb,
                                                     _Float16* __restrict__ kv,
                                                     int n) {
    __shared__ _Float16 smem[2 * 128 * 68];          // staging; reused as transpose tile
    _Float16 (*xs)[68] = (_Float16(*)[68])smem;              // [node][k-half]
    _Float16 (*ws)[68] = (_Float16(*)[68])(smem + 128 * 68); // [feat][k-half]
    const int row0 = blockIdx.x * 128;        // node base
    const int f0   = blockIdx.y * 128;        // feature base: 0,128,256
    const int t = threadIdx.x;
    const int lane = t & 63;
    const int wave = t >> 6;
    const int wr = wave >> 1, wc = wave & 1;  // wr: feat half, wc: node half
    const int l15 = lane & 15, kg = lane >> 4;

    float4v acc[4][4];
#pragma unroll
    for (int i = 0; i < 4; ++i)
#pragma unroll
        for (int j = 0; j < 4; ++j) acc[i][j] = (float4v)0.f;

    const int r5 = t >> 3;        // 0..31
    const int c8 = (t & 7) * 8;   // 0..56

    for (int half = 0; half < 2; ++half) {
        __syncthreads();
#pragma unroll
        for (int p = 0; p < 4; ++p) {
            const int row = p * 32 + r5;
            const int gxr = row0 + row;
            half8v vx = (half8v)(_Float16)0;
            if (gxr < n) vx = *(const half8v*)(xh + (size_t)gxr * FIN_ + half * 64 + c8);
            *(half8v*)&xs[row][c8] = vx;
            *(half8v*)&ws[row][c8] =
                *(const half8v*)(wh + (size_t)(f0 + row) * FIN_ + half * 64 + c8);
        }
        __syncthreads();
#pragma unroll
        for (int ks = 0; ks < 2; ++ks) {
            const int kcol = ks * 32 + kg * 8;
            half8v a[4], b[4];
#pragma unroll
            for (int mi = 0; mi < 4; ++mi)
                a[mi] = *(half8v*)&ws[wr * 64 + mi * 16 + l15][kcol];   // A = W (feat)
#pragma unroll
            for (int ni = 0; ni < 4; ++ni)
                b[ni] = *(half8v*)&xs[wc * 64 + ni * 16 + l15][kcol];   // B = x (node)
#pragma unroll
            for (int mi = 0; mi < 4; ++mi)
#pragma unroll
                for (int ni = 0; ni < 4; ++ni)
                    acc[mi][ni] = __builtin_amdgcn_mfma_f32_16x16x32_f16(
                        a[mi], b[ni], acc[mi][ni], 0, 0, 0);
        }
    }

    // ---- epilogue via LDS transpose tile T[node][feat], pad 136 ----
    __syncthreads();
    _Float16 (*T)[136] = (_Float16(*)[136])smem;
    const bool isq = (f0 == 0);
    const float s = isq ? 0.25f : 1.0f;    // Fh^-0.5 folded into q
#pragma unroll
    for (int mi = 0; mi < 4; ++mi) {
        const int fb = wr * 64 + mi * 16 + kg * 4;
#pragma unroll
        for (int ni = 0; ni < 4; ++ni) {
            const int nl = wc * 64 + ni * 16 + l15;
            union { ushort4 u; _Float16 f[4]; } pk;
#pragma unroll
            for (int r = 0; r < 4; ++r) pk.f[r] = (_Float16)(acc[mi][ni][r] * s);
            *(ushort4*)&T[nl][fb] = pk.u;
        }
    }
    __syncthreads();
#pragma unroll
    for (int i = 0; i < 8; ++i) {
        const int u = t + i * 256;
        const int nl = u >> 4;
        const int cs = (u & 15) * 8;
        const int ng = row0 + nl;
        if (ng >= n) continue;
        const half8v val = *(const half8v*)&T[nl][cs];
        if (isq) *(half8v*)&qb[(size_t)ng * 128 + cs] = val;
        else     *(half8v*)&kv[(size_t)ng * 256 + (f0 - 128) + cs] = val;
    }
}

__device__ __forceinline__ float dot16(uint4 k0, uint4 k1, const half2v* q) {
#if __has_builtin(__builtin_amdgcn_fdot2)
    float s = __builtin_amdgcn_fdot2(u2h(k0.x), q[0], 0.f, false);
    s = __builtin_amdgcn_fdot2(u2h(k0.y), q[1], s, false);
    s = __builtin_amdgcn_fdot2(u2h(k0.z), q[2], s, false);
    s = __builtin_amdgcn_fdot2(u2h(k0.w), q[3], s, false);
    s = __builtin_amdgcn_fdot2(u2h(k1.x), q[4], s, false);
    s = __builtin_amdgcn_fdot2(u2h(k1.y), q[5], s, false);
    s = __builtin_amdgcn_fdot2(u2h(k1.z), q[6], s, false);
    s = __builtin_amdgcn_fdot2(u2h(k1.w), q[7], s, false);
    return s;
#else
    half2v a = u2h(k0.x) * q[0];
    a += u2h(k0.y) * q[1];
    a += u2h(k0.z) * q[2];
    a += u2h(k0.w) * q[3];
    a += u2h(k1.x) * q[4];
    a += u2h(k1.y) * q[5];
    a += u2h(k1.z) * q[6];
    a += u2h(k1.w) * q[7];
    return (float)a[0] + (float)a[1];
#endif
}

// ---------------- edge-parallel attention, f16 kv, packed-f16 math ----------------
// lane = (edge slot j = lane>>3, head h = lane&7). No max subtraction (reference's
// global max cancels; |s| small, exp safe).
__global__ __launch_bounds__(256) void attn_edges_ep(const _Float16* __restrict__ qb,
                                                     const _Float16* __restrict__ kv,
                                                     const int* __restrict__ rowptr,
                                                     const int* __restrict__ dest,
                                                     float* __restrict__ out, int n) {
    const int wave = threadIdx.x >> 6;
    const int node = blockIdx.x * 4 + wave;
    if (node >= n) return;
    const int lane = threadIdx.x & 63;
    const int j = lane >> 3;
    const int h = lane & 7;
    const int ppos = ((j & 1) << 3) | ((j & 2) << 1) | ((j & 4) >> 1);
    float* outp = &out[(size_t)node * FIN_ + h * 16 + ppos];

    const int e0 = rowptr[node];
    const int e1 = rowptr[node + 1];
    if (e0 == e1) {
        *(float2*)outp = make_float2(0.f, 0.f);
        return;
    }

    half2v qh[8];
    {
        const uint4 q0 = *(const uint4*)(qb + (size_t)node * 128 + h * 16);
        const uint4 q1 = *(const uint4*)(qb + (size_t)node * 128 + h * 16 + 8);
        qh[0] = u2h(q0.x); qh[1] = u2h(q0.y); qh[2] = u2h(q0.z); qh[3] = u2h(q0.w);
        qh[4] = u2h(q1.x); qh[5] = u2h(q1.y); qh[6] = u2h(q1.z); qh[7] = u2h(q1.w);
    }

    float lsum = 0.f;
    half2v a8[8];
#pragma unroll
    for (int i = 0; i < 8; ++i) a8[i] = (half2v)(_Float16)0;

    const int hoff = h << 4;
    for (int eb = e0; eb < e1; eb += 16) {
        const int eA = eb + j;
        const int eB = eb + 8 + j;
        const bool vA = eA < e1;
        const bool vB = eB < e1;
        const unsigned dA = (unsigned)dest[vA ? eA : (e1 - 1)];
        const unsigned dB = (unsigned)dest[vB ? eB : (e1 - 1)];
        const unsigned offA = (dA << 8) + hoff;
        const unsigned offB = (dB << 8) + hoff;
        const uint4 k0A = *(const uint4*)(kv + offA);
        const uint4 k1A = *(const uint4*)(kv + offA + 8);
        const uint4 v0A = *(const uint4*)(kv + offA + 128);
        const uint4 v1A = *(const uint4*)(kv + offA + 136);
        const uint4 k0B = *(const uint4*)(kv + offB);
        const uint4 k1B = *(const uint4*)(kv + offB + 8);
        const uint4 v0B = *(const uint4*)(kv + offB + 128);
        const uint4 v1B = *(const uint4*)(kv + offB + 136);

        const float sA = dot16(k0A, k1A, qh);
        const float sB = dot16(k0B, k1B, qh);
        const float pA = vA ? __expf(sA) : 0.f;
        const float pB = vB ? __expf(sB) : 0.f;
        lsum += pA + pB;

        const _Float16 ha = (_Float16)pA, hb = (_Float16)pB;
        const half2v pa = {ha, ha}, pb = {hb, hb};
        a8[0] += pa * u2h(v0A.x) + pb * u2h(v0B.x);
        a8[1] += pa * u2h(v0A.y) + pb * u2h(v0B.y);
        a8[2] += pa * u2h(v0A.z) + pb * u2h(v0B.z);
        a8[3] += pa * u2h(v0A.w) + pb * u2h(v0B.w);
        a8[4] += pa * u2h(v1A.x) + pb * u2h(v1B.x);
        a8[5] += pa * u2h(v1A.y) + pb * u2h(v1B.y);
        a8[6] += pa * u2h(v1A.z) + pb * u2h(v1B.z);
        a8[7] += pa * u2h(v1A.w) + pb * u2h(v1B.w);
    }

    lsum += __shfl_xor(lsum, 8);
    lsum += __shfl_xor(lsum, 16);
    lsum += __shfl_xor(lsum, 32);

    float a16[16];
#pragma unroll
    for (int i = 0; i < 8; ++i) {
        a16[2 * i]     = (float)a8[i][0];
        a16[2 * i + 1] = (float)a8[i][1];
    }

    float r8[8];
    {
        const bool b = (j & 1) != 0;
#pragma unroll
        for (int i = 0; i < 8; ++i) {
            const float keep = b ? a16[i + 8] : a16[i];
            const float send = b ? a16[i] : a16[i + 8];
            r8[i] = keep + __shfl_xor(send, 8);
        }
    }
    float r4[4];
    {
        const bool b = (j & 2) != 0;
#pragma unroll
        for (int i = 0; i < 4; ++i) {
            const float keep = b ? r8[i + 4] : r8[i];
            const float send = b ? r8[i] : r8[i + 4];
            r4[i] = keep + __shfl_xor(send, 16);
        }
    }
    float r2[2];
    {
        const bool b = (j & 4) != 0;
#pragma unroll
        for (int i = 0; i < 2; ++i) {
            const float keep = b ? r4[i + 2] : r4[i];
            const float send = b ? r4[i] : r4[i + 2];
            r2[i] = keep + __shfl_xor(send, 32);
        }
    }

    const float inv = (lsum > 0.f) ? 1.f / lsum : 0.f;
    *(float2*)outp = make_float2(r2[0] * inv, r2[1] * inv);
}

extern "C" void kernel_launch(void* const* d_in, const int* in_sizes, int n_in,
                              void* d_out, int out_size, void* d_ws, size_t ws_size,
                              hipStream_t stream) {
    const float* x = (const float*)d_in[0];
    const float* W = (const float*)d_in[1];
    // d_in[2] = batch : unused by the reference
    const int* ei = (const int*)d_in[3];

    const int n = in_sizes[0] / FIN_;     // 50000
    const int nW = in_sizes[1];           // 384*128
    const int nE = in_sizes[3] / 2;       // 800000
    const int* src = ei;
    const int* dest = ei + nE;

    char* w = (char*)d_ws;
    _Float16* qb = (_Float16*)w;   w += (size_t)n * 128 * 2;            // 12.8 MB
    _Float16* kv = (_Float16*)w;   w += (size_t)n * 256 * 2;            // 25.6 MB
    int* rowptr = (int*)w;         w += ((size_t)(n + 1) * 4 + 15) & ~(size_t)15;
    _Float16* xh = (_Float16*)w;   w += (size_t)n * FIN_ * 2;           // 12.8 MB
    _Float16* wh = (_Float16*)w;
    float* out = (float*)d_out;

    const int nx8 = n * FIN_ / 8, nw8 = nW / 8;
    const int tot = nx8 + nw8 + n + 1;
    cvt_and_rowptr<<<(tot + 255) / 256, 256, 0, stream>>>(x, W, xh, wh, src, rowptr,
                                                          nx8, nw8, nE, n);

    dim3 g1((n + 127) / 128, 3);
    gemm_qkv_mfma<<<g1, 256, 0, stream>>>(xh, wh, qb, kv, n);

    attn_edges_ep<<<(n + 3) / 4, 256, 0, stream>>>(qb, kv, rowptr, dest, out, n);
}

// Round 9
// 96.316 us; speedup vs baseline: 1.0662x; 1.0662x over previous
//
#include <hip/hip_runtime.h>
#include <hip/hip_fp16.h>
#include <math.h>

#define FIN_ 128

typedef _Float16 half2v __attribute__((ext_vector_type(2)));
typedef _Float16 half8v __attribute__((ext_vector_type(8)));
typedef __attribute__((ext_vector_type(4))) float float4v;

__device__ __forceinline__ half2v u2h(unsigned u) {
    union { unsigned u; half2v h; } c; c.u = u; return c.h;
}

// ---------------- fused fp32->f16 convert (x, W) + rowptr build ----------------
// q-scaling (Fh^-0.5 = 0.25) folded into W rows [0,128) here, so the GEMM
// epilogue is scale-free.
__global__ __launch_bounds__(256) void cvt_and_rowptr(const float* __restrict__ x,
                                                      const float* __restrict__ W,
                                                      _Float16* __restrict__ xh,
                                                      _Float16* __restrict__ wh,
                                                      const int* __restrict__ src,
                                                      int* __restrict__ rowptr,
                                                      int nx8, int nw8, int nE, int n) {
    int i = blockIdx.x * blockDim.x + threadIdx.x;
    if (i < nx8 + nw8) {
        const float* s;
        _Float16* d;
        float sc = 1.0f;
        if (i < nx8) { s = x + (size_t)i * 8; d = xh + (size_t)i * 8; }
        else {
            const int k = i - nx8;
            if ((k >> 4) < 128) sc = 0.25f;      // W row = k*8/128 = k>>4; q rows scaled
            s = W + (size_t)k * 8; d = wh + (size_t)k * 8;
        }
        const float4 a = *(const float4*)s;
        const float4 b = *(const float4*)(s + 4);
        half8v r;
        r[0] = (_Float16)(a.x * sc); r[1] = (_Float16)(a.y * sc);
        r[2] = (_Float16)(a.z * sc); r[3] = (_Float16)(a.w * sc);
        r[4] = (_Float16)(b.x * sc); r[5] = (_Float16)(b.y * sc);
        r[6] = (_Float16)(b.z * sc); r[7] = (_Float16)(b.w * sc);
        *(half8v*)d = r;
    } else {
        const int j = i - (nx8 + nw8);
        if (j > n) return;
        int lo = 0, hi = nE;
        while (lo < hi) {
            int mid = (lo + hi) >> 1;
            if (src[mid] < j) lo = mid + 1; else hi = mid;
        }
        rowptr[j] = lo;
    }
}

// ---------------- f16 MFMA GEMM, LDS-free operands, transpose-epilogue --------------
// No A/B staging: fragments load straight from global (fully 64B-line-coalesced:
// lane(l15,kg) reads row l15, bytes [kg*16,kg*16+16) -> 16 fully-used lines per
// wave-load; W is L2-resident, xh L3-resident). No staging barriers at all.
// A = W rows (features), B = x rows (nodes); C[feat][node]; epilogue transposes
// through LDS -> 8 coalesced 16B stores/thread.
//   fblk 0 -> q into qb[node][128] (scale pre-folded); 1 -> k -> kv[node][0..127];
//   2 -> v -> kv[node][128..255]
__global__ __launch_bounds__(256) void gemm_qkv_mfma(const _Float16* __restrict__ xh,
                                                     const _Float16* __restrict__ wh,
                                                     _Float16* __restrict__ qb,
                                                     _Float16* __restrict__ kv,
                                                     int n) {
    __shared__ _Float16 T[128][136];          // transpose tile, 34.8 KB
    const int row0 = blockIdx.x * 128;        // node base
    const int f0   = blockIdx.y * 128;        // feature base: 0,128,256
    const int t = threadIdx.x;
    const int lane = t & 63;
    const int wave = t >> 6;
    const int wr = wave >> 1, wc = wave & 1;  // wr: feat half, wc: node half
    const int l15 = lane & 15, kg = lane >> 4;

    float4v acc[4][4];
#pragma unroll
    for (int i = 0; i < 4; ++i)
#pragma unroll
        for (int j = 0; j < 4; ++j) acc[i][j] = (float4v)0.f;

    int nodeIdx[4];
#pragma unroll
    for (int ni = 0; ni < 4; ++ni) {
        const int nd = row0 + wc * 64 + ni * 16 + l15;
        nodeIdx[ni] = (nd < n) ? nd : 0;      // clamp; OOB rows never stored
    }
    const size_t fbase = (size_t)(f0 + wr * 64 + l15) * FIN_;

#pragma unroll
    for (int half = 0; half < 2; ++half) {
#pragma unroll
        for (int ks = 0; ks < 2; ++ks) {
            const int koff = half * 64 + ks * 32 + kg * 8;
            half8v a[4], b[4];
#pragma unroll
            for (int mi = 0; mi < 4; ++mi)
                a[mi] = *(const half8v*)(wh + fbase + (size_t)mi * 16 * FIN_ + koff);
#pragma unroll
            for (int ni = 0; ni < 4; ++ni)
                b[ni] = *(const half8v*)(xh + (size_t)nodeIdx[ni] * FIN_ + koff);
#pragma unroll
            for (int mi = 0; mi < 4; ++mi)
#pragma unroll
                for (int ni = 0; ni < 4; ++ni)
                    acc[mi][ni] = __builtin_amdgcn_mfma_f32_16x16x32_f16(
                        a[mi], b[ni], acc[mi][ni], 0, 0, 0);
        }
    }

    // ---- epilogue: acc -> T[node][feat] (8B ds_writes), sync, coalesced stores ----
#pragma unroll
    for (int mi = 0; mi < 4; ++mi) {
        const int fb = wr * 64 + mi * 16 + kg * 4;
#pragma unroll
        for (int ni = 0; ni < 4; ++ni) {
            const int nl = wc * 64 + ni * 16 + l15;
            union { ushort4 u; _Float16 f[4]; } pk;
#pragma unroll
            for (int r = 0; r < 4; ++r) pk.f[r] = (_Float16)acc[mi][ni][r];
            *(ushort4*)&T[nl][fb] = pk.u;
        }
    }
    __syncthreads();
    const bool isq = (f0 == 0);
#pragma unroll
    for (int i = 0; i < 8; ++i) {
        const int u = t + i * 256;
        const int nl = u >> 4;
        const int cs = (u & 15) * 8;
        const int ng = row0 + nl;
        if (ng >= n) continue;
        const half8v val = *(const half8v*)&T[nl][cs];
        if (isq) *(half8v*)&qb[(size_t)ng * 128 + cs] = val;
        else     *(half8v*)&kv[(size_t)ng * 256 + (f0 - 128) + cs] = val;
    }
}

__device__ __forceinline__ float dot16(uint4 k0, uint4 k1, const half2v* q) {
#if __has_builtin(__builtin_amdgcn_fdot2)
    float s = __builtin_amdgcn_fdot2(u2h(k0.x), q[0], 0.f, false);
    s = __builtin_amdgcn_fdot2(u2h(k0.y), q[1], s, false);
    s = __builtin_amdgcn_fdot2(u2h(k0.z), q[2], s, false);
    s = __builtin_amdgcn_fdot2(u2h(k0.w), q[3], s, false);
    s = __builtin_amdgcn_fdot2(u2h(k1.x), q[4], s, false);
    s = __builtin_amdgcn_fdot2(u2h(k1.y), q[5], s, false);
    s = __builtin_amdgcn_fdot2(u2h(k1.z), q[6], s, false);
    s = __builtin_amdgcn_fdot2(u2h(k1.w), q[7], s, false);
    return s;
#else
    half2v a = u2h(k0.x) * q[0];
    a += u2h(k0.y) * q[1];
    a += u2h(k0.z) * q[2];
    a += u2h(k0.w) * q[3];
    a += u2h(k1.x) * q[4];
    a += u2h(k1.y) * q[5];
    a += u2h(k1.z) * q[6];
    a += u2h(k1.w) * q[7];
    return (float)a[0] + (float)a[1];
#endif
}

// ---------------- edge-parallel attention, f16 kv, packed-f16 math ----------------
// lane = (edge slot j = lane>>3, head h = lane&7). No max subtraction (reference's
// global max cancels; |s| small, exp safe).
__global__ __launch_bounds__(256) void attn_edges_ep(const _Float16* __restrict__ qb,
                                                     const _Float16* __restrict__ kv,
                                                     const int* __restrict__ rowptr,
                                                     const int* __restrict__ dest,
                                                     float* __restrict__ out, int n) {
    const int wave = threadIdx.x >> 6;
    const int node = blockIdx.x * 4 + wave;
    if (node >= n) return;
    const int lane = threadIdx.x & 63;
    const int j = lane >> 3;
    const int h = lane & 7;
    const int ppos = ((j & 1) << 3) | ((j & 2) << 1) | ((j & 4) >> 1);
    float* outp = &out[(size_t)node * FIN_ + h * 16 + ppos];

    const int e0 = rowptr[node];
    const int e1 = rowptr[node + 1];
    if (e0 == e1) {
        *(float2*)outp = make_float2(0.f, 0.f);
        return;
    }

    half2v qh[8];
    {
        const uint4 q0 = *(const uint4*)(qb + (size_t)node * 128 + h * 16);
        const uint4 q1 = *(const uint4*)(qb + (size_t)node * 128 + h * 16 + 8);
        qh[0] = u2h(q0.x); qh[1] = u2h(q0.y); qh[2] = u2h(q0.z); qh[3] = u2h(q0.w);
        qh[4] = u2h(q1.x); qh[5] = u2h(q1.y); qh[6] = u2h(q1.z); qh[7] = u2h(q1.w);
    }

    float lsum = 0.f;
    half2v a8[8];
#pragma unroll
    for (int i = 0; i < 8; ++i) a8[i] = (half2v)(_Float16)0;

    const int hoff = h << 4;
    for (int eb = e0; eb < e1; eb += 16) {
        const int eA = eb + j;
        const int eB = eb + 8 + j;
        const bool vA = eA < e1;
        const bool vB = eB < e1;
        const unsigned dA = (unsigned)dest[vA ? eA : (e1 - 1)];
        const unsigned dB = (unsigned)dest[vB ? eB : (e1 - 1)];
        const unsigned offA = (dA << 8) + hoff;
        const unsigned offB = (dB << 8) + hoff;
        const uint4 k0A = *(const uint4*)(kv + offA);
        const uint4 k1A = *(const uint4*)(kv + offA + 8);
        const uint4 v0A = *(const uint4*)(kv + offA + 128);
        const uint4 v1A = *(const uint4*)(kv + offA + 136);
        const uint4 k0B = *(const uint4*)(kv + offB);
        const uint4 k1B = *(const uint4*)(kv + offB + 8);
        const uint4 v0B = *(const uint4*)(kv + offB + 128);
        const uint4 v1B = *(const uint4*)(kv + offB + 136);

        const float sA = dot16(k0A, k1A, qh);
        const float sB = dot16(k0B, k1B, qh);
        const float pA = vA ? __expf(sA) : 0.f;
        const float pB = vB ? __expf(sB) : 0.f;
        lsum += pA + pB;

        const _Float16 ha = (_Float16)pA, hb = (_Float16)pB;
        const half2v pa = {ha, ha}, pb = {hb, hb};
        a8[0] += pa * u2h(v0A.x) + pb * u2h(v0B.x);
        a8[1] += pa * u2h(v0A.y) + pb * u2h(v0B.y);
        a8[2] += pa * u2h(v0A.z) + pb * u2h(v0B.z);
        a8[3] += pa * u2h(v0A.w) + pb * u2h(v0B.w);
        a8[4] += pa * u2h(v1A.x) + pb * u2h(v1B.x);
        a8[5] += pa * u2h(v1A.y) + pb * u2h(v1B.y);
        a8[6] += pa * u2h(v1A.z) + pb * u2h(v1B.z);
        a8[7] += pa * u2h(v1A.w) + pb * u2h(v1B.w);
    }

    lsum += __shfl_xor(lsum, 8);
    lsum += __shfl_xor(lsum, 16);
    lsum += __shfl_xor(lsum, 32);

    float a16[16];
#pragma unroll
    for (int i = 0; i < 8; ++i) {
        a16[2 * i]     = (float)a8[i][0];
        a16[2 * i + 1] = (float)a8[i][1];
    }

    float r8[8];
    {
        const bool b = (j & 1) != 0;
#pragma unroll
        for (int i = 0; i < 8; ++i) {
            const float keep = b ? a16[i + 8] : a16[i];
            const float send = b ? a16[i] : a16[i + 8];
            r8[i] = keep + __shfl_xor(send, 8);
        }
    }
    float r4[4];
    {
        const bool b = (j & 2) != 0;
#pragma unroll
        for (int i = 0; i < 4; ++i) {
            const float keep = b ? r8[i + 4] : r8[i];
            const float send = b ? r8[i] : r8[i + 4];
            r4[i] = keep + __shfl_xor(send, 16);
        }
    }
    float r2[2];
    {
        const bool b = (j & 4) != 0;
#pragma unroll
        for (int i = 0; i < 2; ++i) {
            const float keep = b ? r4[i + 2] : r4[i];
            const float send = b ? r4[i] : r4[i + 2];
            r2[i] = keep + __shfl_xor(send, 32);
        }
    }

    const float inv = (lsum > 0.f) ? 1.f / lsum : 0.f;
    *(float2*)outp = make_float2(r2[0] * inv, r2[1] * inv);
}

extern "C" void kernel_launch(void* const* d_in, const int* in_sizes, int n_in,
                              void* d_out, int out_size, void* d_ws, size_t ws_size,
                              hipStream_t stream) {
    const float* x = (const float*)d_in[0];
    const float* W = (const float*)d_in[1];
    // d_in[2] = batch : unused by the reference
    const int* ei = (const int*)d_in[3];

    const int n = in_sizes[0] / FIN_;     // 50000
    const int nW = in_sizes[1];           // 384*128
    const int nE = in_sizes[3] / 2;       // 800000
    const int* src = ei;
    const int* dest = ei + nE;

    char* w = (char*)d_ws;
    _Float16* qb = (_Float16*)w;   w += (size_t)n * 128 * 2;            // 12.8 MB
    _Float16* kv = (_Float16*)w;   w += (size_t)n * 256 * 2;            // 25.6 MB
    int* rowptr = (int*)w;         w += ((size_t)(n + 1) * 4 + 15) & ~(size_t)15;
    _Float16* xh = (_Float16*)w;   w += (size_t)n * FIN_ * 2;           // 12.8 MB
    _Float16* wh = (_Float16*)w;
    float* out = (float*)d_out;

    const int nx8 = n * FIN_ / 8, nw8 = nW / 8;
    const int tot = nx8 + nw8 + n + 1;
    cvt_and_rowptr<<<(tot + 255) / 256, 256, 0, stream>>>(x, W, xh, wh, src, rowptr,
                                                          nx8, nw8, nE, n);

    dim3 g1((n + 127) / 128, 3);
    gemm_qkv_mfma<<<g1, 256, 0, stream>>>(xh, wh, qb, kv, n);

    attn_edges_ep<<<(n + 3) / 4, 256, 0, stream>>>(qb, kv, rowptr, dest, out, n);
}